// Round 1
// baseline (1870.145 us; speedup 1.0000x reference)
//
#include <hip/hip_runtime.h>
#include <math.h>

typedef __attribute__((ext_vector_type(8))) short s8;
typedef __attribute__((ext_vector_type(4))) float f4;
typedef __attribute__((ext_vector_type(4))) unsigned short us4;

#define DEVI __device__ __forceinline__

static const int NPIX = 65536;   // 256*256
static const int BATCH = 4;

DEVI float b2f(unsigned short u) {
    unsigned int v = ((unsigned int)u) << 16;
    float f; __builtin_memcpy(&f, &v, 4); return f;
}
DEVI unsigned short f2b(float f) {
    unsigned int u; __builtin_memcpy(&u, &f, 4);
    unsigned int r = (u + 0x7FFFu + ((u >> 16) & 1u)) >> 16;
    return (unsigned short)r;
}
DEVI float geluf(float x) { return 0.5f * x * (1.0f + erff(x * 0.70710678118f)); }

// ---------------------------------------------------------------------------
// Generic GEMM over channels: Out[b,m,n] = act( sum_k W[m,k]*X[b,k,n] + bias[m] ) (+resid)
// X staged per 64-pixel tile in LDS as bf16 [px][ch]; optional fused LayerNorm over K.
// ---------------------------------------------------------------------------
template<int K, int M, int NW, bool LN, bool DO_GELU, bool RESID, bool OUTBF>
__global__ __launch_bounds__(NW * 64) void gemm_k(
    const void* __restrict__ Xin, const unsigned short* __restrict__ Wb,
    const float* __restrict__ bias, const float* __restrict__ lng,
    const float* __restrict__ lnb, const float* __restrict__ resid,
    void* __restrict__ Out)
{
    constexpr int KP = K + 8;
    __shared__ unsigned short tile[64][KP];
    __shared__ float red1[NW][64];
    __shared__ float red2[NW][64];

    const int tid = threadIdx.x;
    const int bid = blockIdx.x;
    const int b = bid >> 10;              // 1024 tiles of 64 px per batch
    const int n0 = (bid & 1023) * 64;

    const int p = tid & 63;
    const int g = tid >> 6;

    if (LN) {
        constexpr int KG = K / NW;
        const float* X = (const float*)Xin + (size_t)b * K * NPIX + n0 + p;
        float sum = 0.f, ssq = 0.f;
        #pragma unroll 4
        for (int j = 0; j < KG; j++) {
            int c = g * KG + j;
            float v = X[(size_t)c * NPIX];
            sum += v; ssq += v * v;
            tile[p][c] = f2b(v);
        }
        red1[g][p] = sum; red2[g][p] = ssq;
        __syncthreads();
        float s1 = 0.f, s2 = 0.f;
        #pragma unroll
        for (int q = 0; q < NW; q++) { s1 += red1[q][p]; s2 += red2[q][p]; }
        float mu = s1 / (float)K;
        float var = s2 / (float)K - mu * mu;
        float rs = rsqrtf(var + 1e-5f);
        #pragma unroll 4
        for (int j = 0; j < KG; j++) {
            int c = g * KG + j;
            float v = b2f(tile[p][c]);
            v = (v - mu) * rs * lng[c] + lnb[c];
            tile[p][c] = f2b(v);
        }
    } else {
        const unsigned short* X = (const unsigned short*)Xin + (size_t)b * K * NPIX + n0;
        for (int i = tid; i < K * 32; i += NW * 64) {
            int c = i >> 5; int p2 = (i & 31) * 2;
            const unsigned short* src = X + (size_t)c * NPIX + p2;
            unsigned short v0 = src[0], v1 = src[1];
            tile[p2][c] = v0; tile[p2 + 1][c] = v1;
        }
    }
    __syncthreads();

    const int wave = tid >> 6, lane = tid & 63;
    const int lr = lane & 15, lg = lane >> 4;
    constexpr int MW = M / NW;
    constexpr int MT = MW / 16;
    const int m0w = wave * MW;

    f4 acc[MT][4];
    #pragma unroll
    for (int i = 0; i < MT; i++)
        #pragma unroll
        for (int j = 0; j < 4; j++) acc[i][j] = (f4)0.0f;

    #pragma unroll
    for (int k0 = 0; k0 < K; k0 += 32) {
        s8 bf[4];
        #pragma unroll
        for (int nt = 0; nt < 4; nt++)
            bf[nt] = *(const s8*)&tile[nt * 16 + lr][k0 + lg * 8];
        #pragma unroll
        for (int mt = 0; mt < MT; mt++) {
            s8 af = *(const s8*)&Wb[(size_t)(m0w + mt * 16 + lr) * K + k0 + lg * 8];
            #pragma unroll
            for (int nt = 0; nt < 4; nt++)
                acc[mt][nt] = __builtin_amdgcn_mfma_f32_16x16x32_bf16(af, bf[nt], acc[mt][nt], 0, 0, 0);
        }
    }

    #pragma unroll
    for (int mt = 0; mt < MT; mt++) {
        #pragma unroll
        for (int nt = 0; nt < 4; nt++) {
            int col = n0 + nt * 16 + lr;
            #pragma unroll
            for (int r = 0; r < 4; r++) {
                int row = m0w + mt * 16 + lg * 4 + r;
                float v = acc[mt][nt][r] + bias[row];
                if (DO_GELU) v = geluf(v);
                size_t off = ((size_t)b * M + row) * NPIX + col;
                if (RESID) v += resid[off];
                if (OUTBF) ((unsigned short*)Out)[off] = f2b(v);
                else       ((float*)Out)[off] = v;
            }
        }
    }
}

// ---------------------------------------------------------------------------
// Per-row (b, k-channel) online max + log-sum-exp over all 65536 pixels.
// koff[r] = max + log(sum exp(k - max));  p = exp(k - koff) is softmax.
// ---------------------------------------------------------------------------
__global__ __launch_bounds__(256) void krow_k(const unsigned short* __restrict__ qkv,
                                              float* __restrict__ koff)
{
    int r = blockIdx.x;
    int b = r / 192, ch = 192 + (r % 192);
    const unsigned short* Kp = qkv + ((size_t)b * 576 + ch) * NPIX;
    int tid = threadIdx.x;
    float m = -1e30f, s = 0.f;
    for (int i = 0; i < 256; i++) {
        float v = b2f(Kp[tid + (size_t)i * 256]);
        if (v > m) { s = s * __expf(m - v) + 1.f; m = v; }
        else s += __expf(v - m);
    }
    __shared__ float ms[256], ss[256];
    ms[tid] = m; ss[tid] = s;
    __syncthreads();
    for (int off = 128; off > 0; off >>= 1) {
        if (tid < off) {
            float m2 = ms[tid + off], s2 = ss[tid + off];
            float M2 = fmaxf(ms[tid], m2);
            ss[tid] = ss[tid] * __expf(ms[tid] - M2) + s2 * __expf(m2 - M2);
            ms[tid] = M2;
        }
        __syncthreads();
    }
    if (tid == 0) koff[r] = ms[0] + logf(ss[0]);
}

__global__ void zero_k(float* __restrict__ p, int n)
{
    int i = blockIdx.x * 256 + threadIdx.x;
    if (i < n) p[i] = 0.f;
}

__global__ void cvt_k(const float* __restrict__ src, unsigned short* __restrict__ dst, int n)
{
    int i = blockIdx.x * 256 + threadIdx.x;
    if (i < n) dst[i] = f2b(src[i]);
}

// ---------------------------------------------------------------------------
// context: ctxT[b,h,d,c] = sum_n exp(k[c,n]-koff[c]) * v[d,n], via MFMA over n,
// partial per n-chunk, f32 atomicAdd into padded [B][8][32][32].
// ---------------------------------------------------------------------------
__global__ __launch_bounds__(64) void context_k(const unsigned short* __restrict__ qkv,
                                                const float* __restrict__ koff,
                                                float* __restrict__ ctxT)
{
    int bid = blockIdx.x;
    int bh = bid >> 6, chunk = bid & 63;   // 64 chunks of 1024 px
    int b = bh >> 3, h = bh & 7;
    int lane = threadIdx.x, lr = lane & 15, lg = lane >> 4;
    size_t nbase = (size_t)chunk * 1024 + lg * 8;

    int c0 = h * 24 + lr;          // rows 0..15 of head (always valid)
    int c1 = h * 24 + 16 + lr;     // rows 16..31 (valid iff lr<8)
    float ko0 = koff[b * 192 + c0];
    int i1 = b * 192 + c1; if (i1 > 775) i1 = 775;
    float ko1 = koff[i1];
    bool val1 = lr < 8;

    const unsigned short* k0p = qkv + ((size_t)b * 576 + 192 + c0) * NPIX + nbase;
    const unsigned short* k1p = qkv + ((size_t)b * 576 + 192 + c1) * NPIX + nbase;
    const unsigned short* v0p = qkv + ((size_t)b * 576 + 384 + h * 24 + lr) * NPIX + nbase;
    const unsigned short* v1p = qkv + ((size_t)b * 576 + 384 + h * 24 + 16 + lr) * NPIX + nbase;

    f4 acc[2][2];
    #pragma unroll
    for (int i = 0; i < 2; i++) for (int j = 0; j < 2; j++) acc[i][j] = (f4)0.0f;

    for (int s = 0; s < 32; s++) {
        int off = s * 32;
        s8 kr0 = *(const s8*)(k0p + off);
        s8 kr1 = *(const s8*)(k1p + off);
        s8 vr0 = *(const s8*)(v0p + off);
        s8 vr1 = *(const s8*)(v1p + off);
        s8 p0, p1;
        #pragma unroll
        for (int j = 0; j < 8; j++) {
            p0[j] = (short)f2b(__expf(b2f((unsigned short)kr0[j]) - ko0));
            p1[j] = val1 ? (short)f2b(__expf(b2f((unsigned short)kr1[j]) - ko1)) : (short)0;
        }
        acc[0][0] = __builtin_amdgcn_mfma_f32_16x16x32_bf16(p0, vr0, acc[0][0], 0, 0, 0);
        acc[0][1] = __builtin_amdgcn_mfma_f32_16x16x32_bf16(p0, vr1, acc[0][1], 0, 0, 0);
        acc[1][0] = __builtin_amdgcn_mfma_f32_16x16x32_bf16(p1, vr0, acc[1][0], 0, 0, 0);
        acc[1][1] = __builtin_amdgcn_mfma_f32_16x16x32_bf16(p1, vr1, acc[1][1], 0, 0, 0);
    }
    float* base = ctxT + (size_t)(b * 8 + h) * 1024;
    #pragma unroll
    for (int mt = 0; mt < 2; mt++)
        #pragma unroll
        for (int ct = 0; ct < 2; ct++)
            #pragma unroll
            for (int r = 0; r < 4; r++) {
                int c = mt * 16 + lg * 4 + r;   // D row = k-channel index
                int d = ct * 16 + lr;           // D col = v-channel index
                atomicAdd(base + d * 32 + c, acc[mt][ct][r]);
            }
}

// ---------------------------------------------------------------------------
// fused: q-softmax (over hd=24) -> ctx apply (MFMA) -> out-proj GEMM -> + x residual
// writes x2 into Out (f32)
// ---------------------------------------------------------------------------
__global__ __launch_bounds__(256) void qctx_proj_k(
    const unsigned short* __restrict__ qkv, const float* __restrict__ ctxT,
    const unsigned short* __restrict__ outWb, const float* __restrict__ outBias,
    const float* __restrict__ xres, float* __restrict__ Out)
{
    __shared__ unsigned short E[64][264];     // exp(q), [px][h*32+cc], cc 24..31 zeroed
    __shared__ float sden[8][64];
    __shared__ unsigned short outp[64][200];  // out_pre [px][ch]

    int tid = threadIdx.x, bid = blockIdx.x;
    int b = bid >> 10, n0 = (bid & 1023) * 64;
    int p = tid & 63, g = tid >> 6;

    #pragma unroll
    for (int hh = 0; hh < 2; hh++) {
        int h = g * 2 + hh;
        float s = 0.f;
        const unsigned short* Q = qkv + ((size_t)b * 576 + h * 24) * NPIX + n0 + p;
        #pragma unroll 4
        for (int cc = 0; cc < 24; cc++) {
            float e = __expf(b2f(Q[(size_t)cc * NPIX]));
            s += e;
            E[p][h * 32 + cc] = f2b(e);
        }
        #pragma unroll
        for (int cc = 24; cc < 32; cc++) E[p][h * 32 + cc] = 0;
        sden[h][p] = s;
    }
    __syncthreads();

    int wave = tid >> 6, lane = tid & 63, lr = lane & 15, lg = lane >> 4;

    #pragma unroll
    for (int hh = 0; hh < 2; hh++) {
        int h = wave * 2 + hh;
        s8 af[2];
        #pragma unroll
        for (int mt = 0; mt < 2; mt++) {
            const float* cp = ctxT + ((size_t)(b * 8 + h) * 32 + mt * 16 + lr) * 32 + lg * 8;
            s8 a;
            #pragma unroll
            for (int j = 0; j < 8; j++) a[j] = (short)f2b(cp[j]);
            af[mt] = a;
        }
        #pragma unroll
        for (int nt = 0; nt < 4; nt++) {
            s8 bf = *(const s8*)&E[nt * 16 + lr][h * 32 + lg * 8];
            f4 z = (f4)0.0f;
            f4 d0 = __builtin_amdgcn_mfma_f32_16x16x32_bf16(af[0], bf, z, 0, 0, 0);
            f4 d1 = __builtin_amdgcn_mfma_f32_16x16x32_bf16(af[1], bf, z, 0, 0, 0);
            int n = nt * 16 + lr;
            float sinv = 1.0f / sden[h][n];
            us4 w0;
            #pragma unroll
            for (int r = 0; r < 4; r++) w0[r] = f2b(d0[r] * sinv);
            *(us4*)&outp[n][h * 24 + lg * 4] = w0;
            if (lg < 2) {
                us4 w1;
                #pragma unroll
                for (int r = 0; r < 4; r++) w1[r] = f2b(d1[r] * sinv);
                *(us4*)&outp[n][h * 24 + 16 + lg * 4] = w1;
            }
        }
    }
    __syncthreads();

    // proj GEMM: M=192, K=192
    f4 acc[3][4];
    #pragma unroll
    for (int i = 0; i < 3; i++) for (int j = 0; j < 4; j++) acc[i][j] = (f4)0.0f;
    #pragma unroll
    for (int k0 = 0; k0 < 192; k0 += 32) {
        s8 bf[4];
        #pragma unroll
        for (int nt = 0; nt < 4; nt++)
            bf[nt] = *(const s8*)&outp[nt * 16 + lr][k0 + lg * 8];
        #pragma unroll
        for (int mt = 0; mt < 3; mt++) {
            s8 af = *(const s8*)&outWb[(size_t)(wave * 48 + mt * 16 + lr) * 192 + k0 + lg * 8];
            #pragma unroll
            for (int nt = 0; nt < 4; nt++)
                acc[mt][nt] = __builtin_amdgcn_mfma_f32_16x16x32_bf16(af, bf[nt], acc[mt][nt], 0, 0, 0);
        }
    }
    #pragma unroll
    for (int mt = 0; mt < 3; mt++)
        #pragma unroll
        for (int nt = 0; nt < 4; nt++) {
            int col = n0 + nt * 16 + lr;
            #pragma unroll
            for (int r = 0; r < 4; r++) {
                int row = wave * 48 + mt * 16 + lg * 4 + r;
                size_t off = ((size_t)b * 192 + row) * NPIX + col;
                Out[off] = acc[mt][nt][r] + outBias[row] + xres[off];
            }
        }
}

// ---------------------------------------------------------------------------
// depthwise 3x3 (SAME, zero-pad) + gelu, bf16 in/out
// ---------------------------------------------------------------------------
__global__ __launch_bounds__(256) void dwconv_k(
    const unsigned short* __restrict__ h1, const float* __restrict__ w,
    const float* __restrict__ bias, unsigned short* __restrict__ h2)
{
    int cz = blockIdx.z;            // b*384 + c
    int c = cz % 384;
    int x = blockIdx.x * 64 + threadIdx.x;
    int y = blockIdx.y * 4 + threadIdx.y;
    const unsigned short* src = h1 + (size_t)cz * NPIX;
    float wr[9];
    #pragma unroll
    for (int j = 0; j < 9; j++) wr[j] = w[c * 9 + j];
    float a = bias[c];
    #pragma unroll
    for (int dy = -1; dy <= 1; dy++) {
        int yy = y + dy;
        if (yy < 0 || yy > 255) continue;
        #pragma unroll
        for (int dx = -1; dx <= 1; dx++) {
            int xx = x + dx;
            if (xx < 0 || xx > 255) continue;
            a += wr[(dy + 1) * 3 + (dx + 1)] * b2f(src[yy * 256 + xx]);
        }
    }
    h2[(size_t)cz * NPIX + y * 256 + x] = f2b(geluf(a));
}

// ---------------------------------------------------------------------------
extern "C" void kernel_launch(void* const* d_in, const int* in_sizes, int n_in,
                              void* d_out, int out_size, void* d_ws, size_t ws_size,
                              hipStream_t stream)
{
    const float* x    = (const float*)d_in[0];
    const float* ln1g = (const float*)d_in[1];
    const float* ln1b = (const float*)d_in[2];
    const float* qkvw = (const float*)d_in[3];
    const float* qkvb = (const float*)d_in[4];
    const float* outw = (const float*)d_in[5];
    const float* outb = (const float*)d_in[6];
    const float* ln2g = (const float*)d_in[7];
    const float* ln2b = (const float*)d_in[8];
    const float* w1   = (const float*)d_in[9];
    const float* b1   = (const float*)d_in[10];
    const float* dww  = (const float*)d_in[11];
    const float* dwb  = (const float*)d_in[12];
    const float* w2   = (const float*)d_in[13];
    const float* b2   = (const float*)d_in[14];
    float* out = (float*)d_out;

    char* ws = (char*)d_ws;
    // region A (402.7MB): qkv bf16 [4*576+8 rows][65536]; later reused by h1/h2
    unsigned short* qkv = (unsigned short*)ws;
    unsigned short* h1  = (unsigned short*)ws;                          // 201.3MB
    unsigned short* h2  = (unsigned short*)(ws + (size_t)201326592);    // 201.3MB
    size_t off = (size_t)402653184;
    float* koff = (float*)(ws + off); off += 4096;                      // 776 used
    float* ctxT = (float*)(ws + off); off += 131072;                    // [4][8][32][32]
    unsigned short* qkvwb = (unsigned short*)(ws + off); off += 221184;
    unsigned short* outwb = (unsigned short*)(ws + off); off += 73728 * 2;
    unsigned short* w1b   = (unsigned short*)(ws + off); off += 147456;
    unsigned short* w2b   = (unsigned short*)(ws + off); off += 147456;

    // weight conversions (f32 -> bf16)
    cvt_k<<<(110592 + 255) / 256, 256, 0, stream>>>(qkvw, qkvwb, 110592);
    cvt_k<<<(36864 + 255) / 256, 256, 0, stream>>>(outw, outwb, 36864);
    cvt_k<<<(73728 + 255) / 256, 256, 0, stream>>>(w1, w1b, 73728);
    cvt_k<<<(73728 + 255) / 256, 256, 0, stream>>>(w2, w2b, 73728);

    // 1) LN1 + qkv GEMM  (f32 x -> bf16 qkv[4][576][65536])
    gemm_k<192, 576, 6, true, false, false, true>
        <<<4096, 384, 0, stream>>>(x, qkvwb, qkvb, ln1g, ln1b, nullptr, qkv);

    // 2) k-row softmax offsets
    krow_k<<<768, 256, 0, stream>>>(qkv, koff);

    // 3) context accumulation
    zero_k<<<128, 256, 0, stream>>>(ctxT, 32768);
    context_k<<<2048, 64, 0, stream>>>(qkv, koff, ctxT);

    // 4) q softmax + ctx apply + out-proj + residual -> x2 (in d_out, f32)
    qctx_proj_k<<<4096, 256, 0, stream>>>(qkv, ctxT, outwb, outb, x, out);

    // 5) LN2 + w1 GEMM + gelu -> h1 bf16
    gemm_k<192, 384, 4, true, true, false, true>
        <<<4096, 256, 0, stream>>>(out, w1b, b1, ln2g, ln2b, nullptr, h1);

    // 6) depthwise 3x3 + gelu -> h2 bf16
    dwconv_k<<<dim3(4, 64, 1536), dim3(64, 4), 0, stream>>>(h1, dww, dwb, h2);

    // 7) w2 GEMM + bias + x2 residual -> d_out f32
    gemm_k<384, 192, 4, false, false, true, false>
        <<<4096, 256, 0, stream>>>(h2, w2b, b2, nullptr, nullptr, out, out);
}

// Round 2
// 1260.303 us; speedup vs baseline: 1.4839x; 1.4839x over previous
//
#include <hip/hip_runtime.h>
#include <math.h>

typedef __attribute__((ext_vector_type(8))) short s8;
typedef __attribute__((ext_vector_type(8))) unsigned short us8;
typedef __attribute__((ext_vector_type(4))) float f4;
typedef __attribute__((ext_vector_type(4))) unsigned short us4;

#define DEVI __device__ __forceinline__

static const int NPIX = 65536;   // 256*256
static const int BATCH = 4;

DEVI float b2f(unsigned short u) {
    unsigned int v = ((unsigned int)u) << 16;
    float f; __builtin_memcpy(&f, &v, 4); return f;
}
DEVI unsigned short f2b(float f) {
    unsigned int u; __builtin_memcpy(&u, &f, 4);
    unsigned int r = (u + 0x7FFFu + ((u >> 16) & 1u)) >> 16;
    return (unsigned short)r;
}
DEVI float geluf(float x) { return 0.5f * x * (1.0f + erff(x * 0.70710678118f)); }

// ---------------------------------------------------------------------------
// Generic GEMM over channels: Out[b,m,n] = act( sum_k W[m,k]*X[b,k,n] + bias[m] ) (+resid)
// X staged per 64-pixel tile in LDS as bf16 [px][ch]; optional fused LayerNorm over K.
// ---------------------------------------------------------------------------
template<int K, int M, int NW, bool LN, bool DO_GELU, bool RESID, bool OUTBF>
__global__ __launch_bounds__(NW * 64) void gemm_k(
    const void* __restrict__ Xin, const unsigned short* __restrict__ Wb,
    const float* __restrict__ bias, const float* __restrict__ lng,
    const float* __restrict__ lnb, const float* __restrict__ resid,
    void* __restrict__ Out)
{
    constexpr int KP = K + 8;
    __shared__ unsigned short tile[64][KP];
    __shared__ float red1[NW][64];
    __shared__ float red2[NW][64];

    const int tid = threadIdx.x;
    const int bid = blockIdx.x;
    const int b = bid >> 10;              // 1024 tiles of 64 px per batch
    const int n0 = (bid & 1023) * 64;

    const int p = tid & 63;
    const int g = tid >> 6;

    if (LN) {
        constexpr int KG = K / NW;
        const float* X = (const float*)Xin + (size_t)b * K * NPIX + n0 + p;
        float sum = 0.f, ssq = 0.f;
        #pragma unroll 4
        for (int j = 0; j < KG; j++) {
            int c = g * KG + j;
            float v = X[(size_t)c * NPIX];
            sum += v; ssq += v * v;
            tile[p][c] = f2b(v);
        }
        red1[g][p] = sum; red2[g][p] = ssq;
        __syncthreads();
        float s1 = 0.f, s2 = 0.f;
        #pragma unroll
        for (int q = 0; q < NW; q++) { s1 += red1[q][p]; s2 += red2[q][p]; }
        float mu = s1 / (float)K;
        float var = s2 / (float)K - mu * mu;
        float rs = rsqrtf(var + 1e-5f);
        #pragma unroll 4
        for (int j = 0; j < KG; j++) {
            int c = g * KG + j;
            float v = b2f(tile[p][c]);
            v = (v - mu) * rs * lng[c] + lnb[c];
            tile[p][c] = f2b(v);
        }
    } else {
        const unsigned short* X = (const unsigned short*)Xin + (size_t)b * K * NPIX + n0;
        for (int i = tid; i < K * 32; i += NW * 64) {
            int c = i >> 5; int p2 = (i & 31) * 2;
            const unsigned short* src = X + (size_t)c * NPIX + p2;
            unsigned short v0 = src[0], v1 = src[1];
            tile[p2][c] = v0; tile[p2 + 1][c] = v1;
        }
    }
    __syncthreads();

    const int wave = tid >> 6, lane = tid & 63;
    const int lr = lane & 15, lg = lane >> 4;
    constexpr int MW = M / NW;
    constexpr int MT = MW / 16;
    const int m0w = wave * MW;

    f4 acc[MT][4];
    #pragma unroll
    for (int i = 0; i < MT; i++)
        #pragma unroll
        for (int j = 0; j < 4; j++) acc[i][j] = (f4)0.0f;

    #pragma unroll
    for (int k0 = 0; k0 < K; k0 += 32) {
        s8 bf[4];
        #pragma unroll
        for (int nt = 0; nt < 4; nt++)
            bf[nt] = *(const s8*)&tile[nt * 16 + lr][k0 + lg * 8];
        #pragma unroll
        for (int mt = 0; mt < MT; mt++) {
            s8 af = *(const s8*)&Wb[(size_t)(m0w + mt * 16 + lr) * K + k0 + lg * 8];
            #pragma unroll
            for (int nt = 0; nt < 4; nt++)
                acc[mt][nt] = __builtin_amdgcn_mfma_f32_16x16x32_bf16(af, bf[nt], acc[mt][nt], 0, 0, 0);
        }
    }

    #pragma unroll
    for (int mt = 0; mt < MT; mt++) {
        #pragma unroll
        for (int nt = 0; nt < 4; nt++) {
            int col = n0 + nt * 16 + lr;
            #pragma unroll
            for (int r = 0; r < 4; r++) {
                int row = m0w + mt * 16 + lg * 4 + r;
                float v = acc[mt][nt][r] + bias[row];
                if (DO_GELU) v = geluf(v);
                size_t off = ((size_t)b * M + row) * NPIX + col;
                if (RESID) v += resid[off];
                if (OUTBF) ((unsigned short*)Out)[off] = f2b(v);
                else       ((float*)Out)[off] = v;
            }
        }
    }
}

// ---------------------------------------------------------------------------
// Per-row (b, k-channel) online max + log-sum-exp over all 65536 pixels.
// ---------------------------------------------------------------------------
__global__ __launch_bounds__(256) void krow_k(const unsigned short* __restrict__ qkv,
                                              float* __restrict__ koff)
{
    int r = blockIdx.x;
    int b = r / 192, ch = 192 + (r % 192);
    const unsigned short* Kp = qkv + ((size_t)b * 576 + ch) * NPIX;
    int tid = threadIdx.x;
    float m = -1e30f, s = 0.f;
    for (int i = 0; i < 256; i++) {
        float v = b2f(Kp[tid + (size_t)i * 256]);
        if (v > m) { s = s * __expf(m - v) + 1.f; m = v; }
        else s += __expf(v - m);
    }
    __shared__ float ms[256], ss[256];
    ms[tid] = m; ss[tid] = s;
    __syncthreads();
    for (int off = 128; off > 0; off >>= 1) {
        if (tid < off) {
            float m2 = ms[tid + off], s2 = ss[tid + off];
            float M2 = fmaxf(ms[tid], m2);
            ss[tid] = ss[tid] * __expf(ms[tid] - M2) + s2 * __expf(m2 - M2);
            ms[tid] = M2;
        }
        __syncthreads();
    }
    if (tid == 0) koff[r] = ms[0] + logf(ss[0]);
}

__global__ void zero_k(float* __restrict__ p, int n)
{
    int i = blockIdx.x * 256 + threadIdx.x;
    if (i < n) p[i] = 0.f;
}

__global__ void cvt_k(const float* __restrict__ src, unsigned short* __restrict__ dst, int n)
{
    int i = blockIdx.x * 256 + threadIdx.x;
    if (i < n) dst[i] = f2b(src[i]);
}

// ---------------------------------------------------------------------------
// context: ctxT[b,h,d,c] = sum_n exp(k[c,n]-koff[c]) * v[d,n]
// ---------------------------------------------------------------------------
__global__ __launch_bounds__(64) void context_k(const unsigned short* __restrict__ qkv,
                                                const float* __restrict__ koff,
                                                float* __restrict__ ctxT)
{
    int bid = blockIdx.x;
    int bh = bid >> 6, chunk = bid & 63;   // 64 chunks of 1024 px
    int b = bh >> 3, h = bh & 7;
    int lane = threadIdx.x, lr = lane & 15, lg = lane >> 4;
    size_t nbase = (size_t)chunk * 1024 + lg * 8;

    int c0 = h * 24 + lr;
    int c1 = h * 24 + 16 + lr;
    float ko0 = koff[b * 192 + c0];
    int i1 = b * 192 + c1; if (i1 > 775) i1 = 775;
    float ko1 = koff[i1];
    bool val1 = lr < 8;

    const unsigned short* k0p = qkv + ((size_t)b * 576 + 192 + c0) * NPIX + nbase;
    const unsigned short* k1p = qkv + ((size_t)b * 576 + 192 + c1) * NPIX + nbase;
    const unsigned short* v0p = qkv + ((size_t)b * 576 + 384 + h * 24 + lr) * NPIX + nbase;
    const unsigned short* v1p = qkv + ((size_t)b * 576 + 384 + h * 24 + 16 + lr) * NPIX + nbase;

    f4 acc[2][2];
    #pragma unroll
    for (int i = 0; i < 2; i++) for (int j = 0; j < 2; j++) acc[i][j] = (f4)0.0f;

    for (int s = 0; s < 32; s++) {
        int off = s * 32;
        s8 kr0 = *(const s8*)(k0p + off);
        s8 kr1 = *(const s8*)(k1p + off);
        s8 vr0 = *(const s8*)(v0p + off);
        s8 vr1 = *(const s8*)(v1p + off);
        s8 p0, p1;
        #pragma unroll
        for (int j = 0; j < 8; j++) {
            p0[j] = (short)f2b(__expf(b2f((unsigned short)kr0[j]) - ko0));
            p1[j] = val1 ? (short)f2b(__expf(b2f((unsigned short)kr1[j]) - ko1)) : (short)0;
        }
        acc[0][0] = __builtin_amdgcn_mfma_f32_16x16x32_bf16(p0, vr0, acc[0][0], 0, 0, 0);
        acc[0][1] = __builtin_amdgcn_mfma_f32_16x16x32_bf16(p0, vr1, acc[0][1], 0, 0, 0);
        acc[1][0] = __builtin_amdgcn_mfma_f32_16x16x32_bf16(p1, vr0, acc[1][0], 0, 0, 0);
        acc[1][1] = __builtin_amdgcn_mfma_f32_16x16x32_bf16(p1, vr1, acc[1][1], 0, 0, 0);
    }
    float* base = ctxT + (size_t)(b * 8 + h) * 1024;
    #pragma unroll
    for (int mt = 0; mt < 2; mt++)
        #pragma unroll
        for (int ct = 0; ct < 2; ct++)
            #pragma unroll
            for (int r = 0; r < 4; r++) {
                int c = mt * 16 + lg * 4 + r;
                int d = ct * 16 + lr;
                atomicAdd(base + d * 32 + c, acc[mt][ct][r]);
            }
}

// ---------------------------------------------------------------------------
// fused: q-softmax -> ctx apply (MFMA) -> out-proj GEMM -> + x residual
// ---------------------------------------------------------------------------
__global__ __launch_bounds__(256) void qctx_proj_k(
    const unsigned short* __restrict__ qkv, const float* __restrict__ ctxT,
    const unsigned short* __restrict__ outWb, const float* __restrict__ outBias,
    const float* __restrict__ xres, float* __restrict__ Out)
{
    __shared__ unsigned short E[64][264];
    __shared__ float sden[8][64];
    __shared__ unsigned short outp[64][200];

    int tid = threadIdx.x, bid = blockIdx.x;
    int b = bid >> 10, n0 = (bid & 1023) * 64;
    int p = tid & 63, g = tid >> 6;

    #pragma unroll
    for (int hh = 0; hh < 2; hh++) {
        int h = g * 2 + hh;
        float s = 0.f;
        const unsigned short* Q = qkv + ((size_t)b * 576 + h * 24) * NPIX + n0 + p;
        #pragma unroll 4
        for (int cc = 0; cc < 24; cc++) {
            float e = __expf(b2f(Q[(size_t)cc * NPIX]));
            s += e;
            E[p][h * 32 + cc] = f2b(e);
        }
        #pragma unroll
        for (int cc = 24; cc < 32; cc++) E[p][h * 32 + cc] = 0;
        sden[h][p] = s;
    }
    __syncthreads();

    int wave = tid >> 6, lane = tid & 63, lr = lane & 15, lg = lane >> 4;

    #pragma unroll
    for (int hh = 0; hh < 2; hh++) {
        int h = wave * 2 + hh;
        s8 af[2];
        #pragma unroll
        for (int mt = 0; mt < 2; mt++) {
            const float* cp = ctxT + ((size_t)(b * 8 + h) * 32 + mt * 16 + lr) * 32 + lg * 8;
            s8 a;
            #pragma unroll
            for (int j = 0; j < 8; j++) a[j] = (short)f2b(cp[j]);
            af[mt] = a;
        }
        #pragma unroll
        for (int nt = 0; nt < 4; nt++) {
            s8 bf = *(const s8*)&E[nt * 16 + lr][h * 32 + lg * 8];
            f4 z = (f4)0.0f;
            f4 d0 = __builtin_amdgcn_mfma_f32_16x16x32_bf16(af[0], bf, z, 0, 0, 0);
            f4 d1 = __builtin_amdgcn_mfma_f32_16x16x32_bf16(af[1], bf, z, 0, 0, 0);
            int n = nt * 16 + lr;
            float sinv = 1.0f / sden[h][n];
            us4 w0;
            #pragma unroll
            for (int r = 0; r < 4; r++) w0[r] = f2b(d0[r] * sinv);
            *(us4*)&outp[n][h * 24 + lg * 4] = w0;
            if (lg < 2) {
                us4 w1;
                #pragma unroll
                for (int r = 0; r < 4; r++) w1[r] = f2b(d1[r] * sinv);
                *(us4*)&outp[n][h * 24 + 16 + lg * 4] = w1;
            }
        }
    }
    __syncthreads();

    f4 acc[3][4];
    #pragma unroll
    for (int i = 0; i < 3; i++) for (int j = 0; j < 4; j++) acc[i][j] = (f4)0.0f;
    #pragma unroll
    for (int k0 = 0; k0 < 192; k0 += 32) {
        s8 bf[4];
        #pragma unroll
        for (int nt = 0; nt < 4; nt++)
            bf[nt] = *(const s8*)&outp[nt * 16 + lr][k0 + lg * 8];
        #pragma unroll
        for (int mt = 0; mt < 3; mt++) {
            s8 af = *(const s8*)&outWb[(size_t)(wave * 48 + mt * 16 + lr) * 192 + k0 + lg * 8];
            #pragma unroll
            for (int nt = 0; nt < 4; nt++)
                acc[mt][nt] = __builtin_amdgcn_mfma_f32_16x16x32_bf16(af, bf[nt], acc[mt][nt], 0, 0, 0);
        }
    }
    #pragma unroll
    for (int mt = 0; mt < 3; mt++)
        #pragma unroll
        for (int nt = 0; nt < 4; nt++) {
            int col = n0 + nt * 16 + lr;
            #pragma unroll
            for (int r = 0; r < 4; r++) {
                int row = wave * 48 + mt * 16 + lg * 4 + r;
                size_t off = ((size_t)b * 192 + row) * NPIX + col;
                Out[off] = acc[mt][nt][r] + outBias[row] + xres[off];
            }
        }
}

// ---------------------------------------------------------------------------
// depthwise 3x3 (SAME, zero-pad) + gelu, bf16 in/out — LDS-tiled, vectorized.
// Block: one channel plane strip, 256 wide x 16 rows. LDS: 18x256 bf16.
// Thread t: columns (t&31)*8..+7, rows (t>>5)*2 + {0,1}.
// ---------------------------------------------------------------------------
__global__ __launch_bounds__(256) void dwconv_k(
    const unsigned short* __restrict__ h1, const float* __restrict__ w,
    const float* __restrict__ bias, unsigned short* __restrict__ h2)
{
    __shared__ unsigned short tile[18][256];
    const int cz = blockIdx.y;            // b*384 + c
    const int c = cz % 384;
    const int y0 = blockIdx.x * 16;
    const int tid = threadIdx.x;
    const unsigned short* src = h1 + (size_t)cz * NPIX;

    // stage 18 rows (y0-1 .. y0+16) x 256 cols as 16B vectors
    #pragma unroll
    for (int j0 = 0; j0 < 576; j0 += 256) {
        int j = j0 + tid;
        if (j < 576) {
            int r = j >> 5, seg = (j & 31) * 8;
            int yy = y0 - 1 + r;
            us8 v;
            if (yy >= 0 && yy <= 255) v = *(const us8*)(src + yy * 256 + seg);
            else { us8 z = {0,0,0,0,0,0,0,0}; v = z; }
            *(us8*)&tile[r][seg] = v;
        }
    }

    float wr[9];
    #pragma unroll
    for (int j = 0; j < 9; j++) wr[j] = w[c * 9 + j];
    const float bi = bias[c];
    __syncthreads();

    const int x0 = (tid & 31) * 8;
    const int orow = (tid >> 5) * 2;      // 0,2,..,14

    #pragma unroll
    for (int rr = 0; rr < 2; rr++) {
        const int o = orow + rr;          // output row within strip
        float a[8];
        #pragma unroll
        for (int i = 0; i < 8; i++) a[i] = bi;
        #pragma unroll
        for (int dy = 0; dy < 3; dy++) {
            const int tr = o + dy;        // tile row (o maps to tile row o+1 for dy=-1..1)
            us8 v = *(const us8*)&tile[tr][x0];
            float f[8];
            #pragma unroll
            for (int i = 0; i < 8; i++) f[i] = b2f(v[i]);
            float lft = (x0 > 0)   ? b2f(tile[tr][x0 - 1]) : 0.f;
            float rgt = (x0 < 248) ? b2f(tile[tr][x0 + 8]) : 0.f;
            const float w0 = wr[dy * 3 + 0], w1 = wr[dy * 3 + 1], w2 = wr[dy * 3 + 2];
            a[0] += w0 * lft;
            #pragma unroll
            for (int i = 1; i < 8; i++) a[i] += w0 * f[i - 1];
            #pragma unroll
            for (int i = 0; i < 8; i++) a[i] += w1 * f[i];
            #pragma unroll
            for (int i = 0; i < 7; i++) a[i] += w2 * f[i + 1];
            a[7] += w2 * rgt;
        }
        us8 ov;
        #pragma unroll
        for (int i = 0; i < 8; i++) ov[i] = f2b(geluf(a[i]));
        *(us8*)(h2 + (size_t)cz * NPIX + (y0 + o) * 256 + x0) = ov;
    }
}

// ---------------------------------------------------------------------------
extern "C" void kernel_launch(void* const* d_in, const int* in_sizes, int n_in,
                              void* d_out, int out_size, void* d_ws, size_t ws_size,
                              hipStream_t stream)
{
    const float* x    = (const float*)d_in[0];
    const float* ln1g = (const float*)d_in[1];
    const float* ln1b = (const float*)d_in[2];
    const float* qkvw = (const float*)d_in[3];
    const float* qkvb = (const float*)d_in[4];
    const float* outw = (const float*)d_in[5];
    const float* outb = (const float*)d_in[6];
    const float* ln2g = (const float*)d_in[7];
    const float* ln2b = (const float*)d_in[8];
    const float* w1   = (const float*)d_in[9];
    const float* b1   = (const float*)d_in[10];
    const float* dww  = (const float*)d_in[11];
    const float* dwb  = (const float*)d_in[12];
    const float* w2   = (const float*)d_in[13];
    const float* b2   = (const float*)d_in[14];
    float* out = (float*)d_out;

    char* ws = (char*)d_ws;
    unsigned short* qkv = (unsigned short*)ws;
    unsigned short* h1  = (unsigned short*)ws;                          // 201.3MB
    unsigned short* h2  = (unsigned short*)(ws + (size_t)201326592);    // 201.3MB
    size_t off = (size_t)402653184;
    float* koff = (float*)(ws + off); off += 4096;
    float* ctxT = (float*)(ws + off); off += 131072;
    unsigned short* qkvwb = (unsigned short*)(ws + off); off += 221184;
    unsigned short* outwb = (unsigned short*)(ws + off); off += 73728 * 2;
    unsigned short* w1b   = (unsigned short*)(ws + off); off += 147456;
    unsigned short* w2b   = (unsigned short*)(ws + off); off += 147456;

    cvt_k<<<(110592 + 255) / 256, 256, 0, stream>>>(qkvw, qkvwb, 110592);
    cvt_k<<<(36864 + 255) / 256, 256, 0, stream>>>(outw, outwb, 36864);
    cvt_k<<<(73728 + 255) / 256, 256, 0, stream>>>(w1, w1b, 73728);
    cvt_k<<<(73728 + 255) / 256, 256, 0, stream>>>(w2, w2b, 73728);

    // 1) LN1 + qkv GEMM
    gemm_k<192, 576, 6, true, false, false, true>
        <<<4096, 384, 0, stream>>>(x, qkvwb, qkvb, ln1g, ln1b, nullptr, qkv);

    // 2) k-row softmax offsets
    krow_k<<<768, 256, 0, stream>>>(qkv, koff);

    // 3) context accumulation
    zero_k<<<128, 256, 0, stream>>>(ctxT, 32768);
    context_k<<<2048, 64, 0, stream>>>(qkv, koff, ctxT);

    // 4) q softmax + ctx apply + out-proj + residual -> x2
    qctx_proj_k<<<4096, 256, 0, stream>>>(qkv, ctxT, outwb, outb, x, out);

    // 5) LN2 + w1 GEMM + gelu -> h1
    gemm_k<192, 384, 4, true, true, false, true>
        <<<4096, 256, 0, stream>>>(out, w1b, b1, ln2g, ln2b, nullptr, h1);

    // 6) depthwise 3x3 + gelu -> h2  (LDS-tiled, vectorized)
    dwconv_k<<<dim3(16, 1536), 256, 0, stream>>>(h1, dww, dwb, h2);

    // 7) w2 GEMM + bias + x2 residual -> d_out
    gemm_k<384, 192, 4, false, false, true, false>
        <<<4096, 256, 0, stream>>>(h2, w2b, b2, nullptr, nullptr, out, out);
}